// Round 4
// baseline (881.599 us; speedup 1.0000x reference)
//
#include <hip/hip_runtime.h>
#include <math.h>

namespace {

constexpr int kB = 16, kT = 32, kN = 64, kE = 64, kFIN = 2, kD = 64, kH = 4, kL = 2, kSH = 128;
constexpr int kG = kB * kT;    // 512 graphs
constexpr int kET = kE + kN;   // 128 edges incl. self loops

// ---------------- GAT LDS layout (float indices) ----------------
constexpr int HN   = 0;                    // h[n][k] stride 68 (4352)
constexpr int XLo  = HN + 64 * 68;         // xl[4][64*65] (xl[hh*4160 + n*65 + d]) (16640)
constexpr int WREG = XLo + 4 * 4160;       // W staged [256][68] (17408); xr[4][4160] + tmp + LN scratch live here too
constexpr int XRo  = WREG;
constexpr int LG   = WREG + 256 * 68;      // logitT[4][128]
constexpr int AL   = LG + 4 * 128;         // alphaT[4][128]
constexpr int MB   = AL + 4 * 128;         // mT[4][64]
constexpr int SB   = MB + 4 * 64;          // 1/sum T[4][64]
constexpr int FEND = SB + 4 * 64;          // 39936 floats
// LN scratch in dead xr region (past tmp[64][65]):
constexpr int SC1 = XRo + 4160;
constexpr int SC2 = SC1 + 512;
constexpr int SMU = SC2 + 512;
constexpr int SRS = SMU + 64;
// int section
constexpr int ISRC = 0, IDST = 128, IOFF = 256, IEL = 321;
constexpr int NINT = IEL + 128;            // 449 ints
constexpr size_t GAT_LDS = size_t(FEND) * 4 + size_t(NINT) * 4;  // 161,540 B <= 163,840

// ---------------- LSTM LDS layout ----------------
constexpr int ES = 0;                  // embS[32][64]
constexpr int YS = ES + 32 * 64;       // ys[32][128]
constexpr int HB = YS + 32 * 128;      // h[128]
constexpr int CB = HB + 128;           // c[128]
constexpr int ZB = CB + 128;           // zbuf[512]
constexpr int ZX = ZB + 512;           // zx[32][512]
constexpr int LSTM_FLOATS = ZX + 32 * 512;
constexpr size_t LSTM_LDS = size_t(LSTM_FLOATS) * 4;  // 93,184 B

__device__ __forceinline__ float fsig(float x) {
    return __builtin_amdgcn_rcpf(1.f + __expf(-x));
}
__device__ __forceinline__ float ftanh(float x) {
    return 1.f - 2.f * __builtin_amdgcn_rcpf(1.f + __expf(2.f * x));
}

} // namespace

// =====================================================================
// GAT kernel: one block per graph, 512 threads (8 waves), 1 block/CU.
// Transforms: k-major register tiling, all LDS accesses conflict-free:
//   h[n][k], W[c][k] both stride 68; per k4-step each thread reads
//   8 h-float4 (rows ng+8i -> 8 distinct bank-quads, 8x broadcast) and
//   4 W-float4 (cols cwave+cl+8j -> 8 distinct bank-quads, 8x broadcast).
// =====================================================================
__global__ __launch_bounds__(512, 2)
void gat_kernel(const float* __restrict__ x, const int* __restrict__ eidx,
                const float* __restrict__ projW, const float* __restrict__ projb,
                const float* __restrict__ gWl, const float* __restrict__ gWr,
                const float* __restrict__ gatt, const float* __restrict__ gb,
                const float* __restrict__ lng, const float* __restrict__ lnb,
                float* __restrict__ emb)
{
    extern __shared__ float sm[];
    int* ib = (int*)(sm + FEND);
    const int g = blockIdx.x;
    const int t = threadIdx.x;

    // ---- edges + self loops ----
    if (t < kET) {
        int s, d;
        if (t < kE) { s = eidx[g * 2 * kE + t]; d = eidx[g * 2 * kE + kE + t]; }
        else        { s = t - kE; d = s; }
        ib[ISRC + t] = s;
        ib[IDST + t] = d;
    }
    // ---- input projection + ReLU -> h[n][k] (stride 68) ----
    #pragma unroll
    for (int r = 0; r < 8; ++r) {
        int p = t + 512 * r;
        int d = p & 63, n = p >> 6;           // d fast: conflict-free LDS write sweep; n wave-uniform
        float x0 = x[g * kN * kFIN + n * kFIN + 0];
        float x1 = x[g * kN * kFIN + n * kFIN + 1];
        float v = fmaf(x0, projW[d * kFIN + 0], fmaf(x1, projW[d * kFIN + 1], projb[d]));
        sm[HN + n * 68 + d] = fmaxf(v, 0.f);
    }
    __syncthreads();
    // ---- CSR build (deterministic, no atomics) ----
    if (t < kN) {
        int c = 0;
        for (int e = 0; e < kET; ++e) c += (ib[IDST + e] == t) ? 1 : 0;
        ib[IOFF + t + 1] = c;
    }
    __syncthreads();
    if (t == 0) {
        ib[IOFF + 0] = 0;
        for (int n = 0; n < kN; ++n) ib[IOFF + n + 1] += ib[IOFF + n];
    }
    __syncthreads();
    if (t < kN) {
        int pos = ib[IOFF + t];
        for (int e = 0; e < kET; ++e)
            if (ib[IDST + e] == t) ib[IEL + pos++] = e;
    }
    __syncthreads();

    const int wv = t >> 6;        // wave 0..7
    const int ln = t & 63;
    const int cl = ln & 7;        // c-lane
    const int ng = ln >> 3;       // n-group 0..7
    const int cwave = wv * 32;

    for (int l = 0; l < kL; ++l) {
        // ======== transforms: half 0 -> xl (XLo), half 1 -> xr (WREG, overwrites W) ========
        for (int half = 0; half < 2; ++half) {
            const float* Wg = (half ? gWr : gWl) + l * 256 * 64;
            // stage W[c][k] stride 68 (pure float4 sweep, no transpose)
            #pragma unroll
            for (int it = 0; it < 8; ++it) {
                int p = t + 512 * it;               // float4 index into W [256][64]
                float4 v = ((const float4*)Wg)[p];
                int c = p >> 4, k4 = p & 15;
                *(float4*)&sm[WREG + c * 68 + k4 * 4] = v;
            }
            __syncthreads();
            float acc[8][4];
            #pragma unroll
            for (int i = 0; i < 8; ++i)
                #pragma unroll
                for (int j = 0; j < 4; ++j) acc[i][j] = 0.f;
            #pragma unroll 2
            for (int k4 = 0; k4 < 16; ++k4) {
                float4 h4[8], w4[4];
                #pragma unroll
                for (int i = 0; i < 8; ++i)
                    h4[i] = *(const float4*)&sm[HN + (ng + 8 * i) * 68 + k4 * 4];
                #pragma unroll
                for (int j = 0; j < 4; ++j)
                    w4[j] = *(const float4*)&sm[WREG + (cwave + cl + 8 * j) * 68 + k4 * 4];
                #pragma unroll
                for (int i = 0; i < 8; ++i)
                    #pragma unroll
                    for (int j = 0; j < 4; ++j) {
                        acc[i][j] = fmaf(h4[i].x, w4[j].x, acc[i][j]);
                        acc[i][j] = fmaf(h4[i].y, w4[j].y, acc[i][j]);
                        acc[i][j] = fmaf(h4[i].z, w4[j].z, acc[i][j]);
                        acc[i][j] = fmaf(h4[i].w, w4[j].w, acc[i][j]);
                    }
            }
            __syncthreads();   // drain W reads before overwriting WREG / restaging
            float* dst = sm + (half ? XRo : XLo);
            #pragma unroll
            for (int i = 0; i < 8; ++i) {
                int n = ng + 8 * i;
                #pragma unroll
                for (int j = 0; j < 4; ++j) {
                    int c = cwave + cl + 8 * j;
                    dst[(c >> 6) * 4160 + n * 65 + (c & 63)] = acc[i][j];
                }
            }
            __syncthreads();
        }
        // ---- edge logits ----
        {
            const int e = t & 127, hh = t >> 7;
            const int s = ib[ISRC + e], d_ = ib[IDST + e];
            const float* av = gatt + (l * kH + hh) * kD;
            const float* pl = sm + XLo + hh * 4160 + s * 65;
            const float* pr = sm + XRo + hh * 4160 + d_ * 65;
            float acc = 0.f;
            #pragma unroll 8
            for (int dd = 0; dd < 64; ++dd) {
                float v = pl[dd] + pr[dd];
                v = (v > 0.f) ? v : 0.2f * v;
                acc = fmaf(av[dd], v, acc);
            }
            sm[LG + hh * 128 + e] = acc;
        }
        __syncthreads();
        // ---- segment max & sum ----
        if (t < 256) {
            const int n = t & 63, hh = t >> 6;
            const int i0 = ib[IOFF + n], i1 = ib[IOFF + n + 1];
            float m = -3.0e38f;
            for (int i = i0; i < i1; ++i) m = fmaxf(m, sm[LG + hh * 128 + ib[IEL + i]]);
            float ssum = 0.f;
            for (int i = i0; i < i1; ++i) ssum += __expf(sm[LG + hh * 128 + ib[IEL + i]] - m);
            sm[MB + hh * 64 + n] = m;
            sm[SB + hh * 64 + n] = __builtin_amdgcn_rcpf(ssum);
        }
        __syncthreads();
        // ---- alpha ----
        {
            const int e = t & 127, hh = t >> 7;
            const int d_ = ib[IDST + e];
            sm[AL + hh * 128 + e] =
                __expf(sm[LG + hh * 128 + e] - sm[MB + hh * 64 + d_]) * sm[SB + hh * 64 + d_];
        }
        __syncthreads();
        // ---- aggregate + head-mean + bias -> tmp[64][65] at XRo (xr dead) ----
        #pragma unroll
        for (int r = 0; r < 8; ++r) {
            int p = t + 512 * r;
            int n = p >> 6, dd = p & 63;       // n wave-uniform; dd = lane -> sweeps
            const int i0 = ib[IOFF + n], i1 = ib[IOFF + n + 1];
            float acc = 0.f;
            for (int i = i0; i < i1; ++i) {
                int e = ib[IEL + i];
                int s = ib[ISRC + e];
                const float* xs = sm + XLo + s * 65 + dd;
                acc = fmaf(sm[AL + 0 * 128 + e], xs[0 * 4160], acc);
                acc = fmaf(sm[AL + 1 * 128 + e], xs[1 * 4160], acc);
                acc = fmaf(sm[AL + 2 * 128 + e], xs[2 * 4160], acc);
                acc = fmaf(sm[AL + 3 * 128 + e], xs[3 * 4160], acc);
            }
            sm[XRo + n * 65 + dd] = acc * 0.25f + gb[l * kD + dd];
        }
        __syncthreads();
        // ---- layernorm partials ----
        {
            const int n = t >> 3, q = t & 7;
            const float* row = sm + XRo + n * 65 + q * 8;
            float s1 = 0.f, s2 = 0.f;
            #pragma unroll
            for (int i = 0; i < 8; ++i) { float v = row[i]; s1 += v; s2 = fmaf(v, v, s2); }
            sm[SC1 + n * 8 + q] = s1;
            sm[SC2 + n * 8 + q] = s2;
        }
        __syncthreads();
        if (t < kN) {
            float s1 = 0.f, s2 = 0.f;
            #pragma unroll
            for (int q = 0; q < 8; ++q) { s1 += sm[SC1 + t * 8 + q]; s2 += sm[SC2 + t * 8 + q]; }
            float m   = s1 * (1.f / 64.f);
            float var = s2 * (1.f / 64.f) - m * m;
            sm[SMU + t] = m;
            sm[SRS + t] = rsqrtf(var + 1e-5f);
        }
        __syncthreads();
        // ---- apply LN + ReLU -> h[n][k] ----
        #pragma unroll
        for (int r = 0; r < 8; ++r) {
            int p = t + 512 * r;
            int dd = p & 63, n = p >> 6;       // dd fast: both read & write sweep
            float v  = sm[XRo + n * 65 + dd];
            float y  = fmaf(lng[l * kD + dd] * (v - sm[SMU + n]), sm[SRS + n], lnb[l * kD + dd]);
            sm[HN + n * 68 + dd] = fmaxf(y, 0.f);
        }
        __syncthreads();
    }
    // ---- global mean pool ----
    if (t < kD) {
        float s = 0.f;
        #pragma unroll 8
        for (int n = 0; n < kN; ++n) s += sm[HN + n * 68 + t];
        emb[g * kD + t] = s * (1.f / 64.f);
    }
}

// =====================================================================
// LSTM (2 layers, T=32) + MLP head: one block per batch element (16).
// 256 threads (4 waves, 1/SIMD -> 512-VGPR budget); each thread owns
// TWO gate rows (j, j+256): halves the broadcast h-read instruction
// count per step (the measured LDS bottleneck).
// =====================================================================
__global__ __launch_bounds__(256, 1)
void lstm_head_kernel(const float* __restrict__ emb,
                      const float* __restrict__ W0ih, const float* __restrict__ W0hh,
                      const float* __restrict__ b0ih, const float* __restrict__ b0hh,
                      const float* __restrict__ W1ih, const float* __restrict__ W1hh,
                      const float* __restrict__ b1ih, const float* __restrict__ b1hh,
                      const float* __restrict__ hW1, const float* __restrict__ hb1,
                      const float* __restrict__ hW2, const float* __restrict__ hb2,
                      const float* __restrict__ hW3, const float* __restrict__ hb3,
                      float* __restrict__ outp)
{
    extern __shared__ float sm[];
    const int bb = blockIdx.x;
    const int j  = threadIdx.x;      // 0..255
    const int rA = j, rB = j + 256;

    ((float4*)(sm + ES))[j]       = ((const float4*)(emb + bb * kT * kD))[j];
    ((float4*)(sm + ES))[j + 256] = ((const float4*)(emb + bb * kT * kD))[j + 256];
    if (j < kSH) { sm[HB + j] = 0.f; sm[CB + j] = 0.f; }
    __syncthreads();

    // ---- layer0 x-part: rows rA, rB over emb[t][0..63] ----
    {
        float wA[64], wB[64];
        const float4* wra = (const float4*)(W0ih + rA * 64);
        const float4* wrb = (const float4*)(W0ih + rB * 64);
        #pragma unroll
        for (int k4 = 0; k4 < 16; ++k4) {
            float4 a = wra[k4], b = wrb[k4];
            wA[4*k4+0]=a.x; wA[4*k4+1]=a.y; wA[4*k4+2]=a.z; wA[4*k4+3]=a.w;
            wB[4*k4+0]=b.x; wB[4*k4+1]=b.y; wB[4*k4+2]=b.z; wB[4*k4+3]=b.w;
        }
        const float biasA = b0ih[rA] + b0hh[rA];
        const float biasB = b0ih[rB] + b0hh[rB];
        for (int tt = 0; tt < kT; ++tt) {
            const float4* ev = (const float4*)(sm + ES + tt * 64);
            float a0 = biasA, a1 = 0.f, b0 = biasB, b1 = 0.f;
            #pragma unroll
            for (int k4 = 0; k4 < 16; k4 += 2) {
                float4 u = ev[k4], v = ev[k4 + 1];
                a0 = fmaf(wA[4*k4+0], u.x, a0); a0 = fmaf(wA[4*k4+1], u.y, a0);
                a0 = fmaf(wA[4*k4+2], u.z, a0); a0 = fmaf(wA[4*k4+3], u.w, a0);
                a1 = fmaf(wA[4*k4+4], v.x, a1); a1 = fmaf(wA[4*k4+5], v.y, a1);
                a1 = fmaf(wA[4*k4+6], v.z, a1); a1 = fmaf(wA[4*k4+7], v.w, a1);
                b0 = fmaf(wB[4*k4+0], u.x, b0); b0 = fmaf(wB[4*k4+1], u.y, b0);
                b0 = fmaf(wB[4*k4+2], u.z, b0); b0 = fmaf(wB[4*k4+3], u.w, b0);
                b1 = fmaf(wB[4*k4+4], v.x, b1); b1 = fmaf(wB[4*k4+5], v.y, b1);
                b1 = fmaf(wB[4*k4+6], v.z, b1); b1 = fmaf(wB[4*k4+7], v.w, b1);
            }
            sm[ZX + tt * 512 + rA] = a0 + a1;
            sm[ZX + tt * 512 + rB] = b0 + b1;
        }
    }
    __syncthreads();
    // ---- layer0 recurrence ----
    {
        float wA[128], wB[128];
        const float4* wra = (const float4*)(W0hh + rA * 128);
        const float4* wrb = (const float4*)(W0hh + rB * 128);
        #pragma unroll
        for (int k4 = 0; k4 < 32; ++k4) {
            float4 a = wra[k4], b = wrb[k4];
            wA[4*k4+0]=a.x; wA[4*k4+1]=a.y; wA[4*k4+2]=a.z; wA[4*k4+3]=a.w;
            wB[4*k4+0]=b.x; wB[4*k4+1]=b.y; wB[4*k4+2]=b.z; wB[4*k4+3]=b.w;
        }
        for (int tt = 0; tt < kT; ++tt) {
            const float4* hb4 = (const float4*)(sm + HB);
            float a0 = sm[ZX + tt * 512 + rA], a1 = 0.f;
            float b0 = sm[ZX + tt * 512 + rB], b1 = 0.f;
            #pragma unroll 8
            for (int k4 = 0; k4 < 32; k4 += 2) {
                float4 u = hb4[k4], v = hb4[k4 + 1];
                a0 = fmaf(wA[4*k4+0], u.x, a0); a0 = fmaf(wA[4*k4+1], u.y, a0);
                a0 = fmaf(wA[4*k4+2], u.z, a0); a0 = fmaf(wA[4*k4+3], u.w, a0);
                a1 = fmaf(wA[4*k4+4], v.x, a1); a1 = fmaf(wA[4*k4+5], v.y, a1);
                a1 = fmaf(wA[4*k4+6], v.z, a1); a1 = fmaf(wA[4*k4+7], v.w, a1);
                b0 = fmaf(wB[4*k4+0], u.x, b0); b0 = fmaf(wB[4*k4+1], u.y, b0);
                b0 = fmaf(wB[4*k4+2], u.z, b0); b0 = fmaf(wB[4*k4+3], u.w, b0);
                b1 = fmaf(wB[4*k4+4], v.x, b1); b1 = fmaf(wB[4*k4+5], v.y, b1);
                b1 = fmaf(wB[4*k4+6], v.z, b1); b1 = fmaf(wB[4*k4+7], v.w, b1);
            }
            float zA = a0 + a1, zB = b0 + b1;
            sm[ZB + rA] = fsig(zA);                                // i or f gate
            sm[ZB + rB] = (j < 128) ? ftanh(zB) : fsig(zB);        // g or o gate
            __syncthreads();
            if (j < kSH) {
                float c = fmaf(sm[ZB + 128 + j], sm[CB + j], sm[ZB + j] * sm[ZB + 256 + j]);
                sm[CB + j] = c;
                float h = sm[ZB + 384 + j] * ftanh(c);
                sm[HB + j] = h;
                sm[YS + tt * 128 + j] = h;
            }
            __syncthreads();
        }
    }
    // ---- layer1 x-part ----
    {
        float wA[128], wB[128];
        const float4* wra = (const float4*)(W1ih + rA * 128);
        const float4* wrb = (const float4*)(W1ih + rB * 128);
        #pragma unroll
        for (int k4 = 0; k4 < 32; ++k4) {
            float4 a = wra[k4], b = wrb[k4];
            wA[4*k4+0]=a.x; wA[4*k4+1]=a.y; wA[4*k4+2]=a.z; wA[4*k4+3]=a.w;
            wB[4*k4+0]=b.x; wB[4*k4+1]=b.y; wB[4*k4+2]=b.z; wB[4*k4+3]=b.w;
        }
        const float biasA = b1ih[rA] + b1hh[rA];
        const float biasB = b1ih[rB] + b1hh[rB];
        for (int tt = 0; tt < kT; ++tt) {
            const float4* yv = (const float4*)(sm + YS + tt * 128);
            float a0 = biasA, a1 = 0.f, b0 = biasB, b1 = 0.f;
            #pragma unroll 8
            for (int k4 = 0; k4 < 32; k4 += 2) {
                float4 u = yv[k4], v = yv[k4 + 1];
                a0 = fmaf(wA[4*k4+0], u.x, a0); a0 = fmaf(wA[4*k4+1], u.y, a0);
                a0 = fmaf(wA[4*k4+2], u.z, a0); a0 = fmaf(wA[4*k4+3], u.w, a0);
                a1 = fmaf(wA[4*k4+4], v.x, a1); a1 = fmaf(wA[4*k4+5], v.y, a1);
                a1 = fmaf(wA[4*k4+6], v.z, a1); a1 = fmaf(wA[4*k4+7], v.w, a1);
                b0 = fmaf(wB[4*k4+0], u.x, b0); b0 = fmaf(wB[4*k4+1], u.y, b0);
                b0 = fmaf(wB[4*k4+2], u.z, b0); b0 = fmaf(wB[4*k4+3], u.w, b0);
                b1 = fmaf(wB[4*k4+4], v.x, b1); b1 = fmaf(wB[4*k4+5], v.y, b1);
                b1 = fmaf(wB[4*k4+6], v.z, b1); b1 = fmaf(wB[4*k4+7], v.w, b1);
            }
            sm[ZX + tt * 512 + rA] = a0 + a1;
            sm[ZX + tt * 512 + rB] = b0 + b1;
        }
    }
    if (j < kSH) { sm[HB + j] = 0.f; sm[CB + j] = 0.f; }
    __syncthreads();
    // ---- layer1 recurrence ----
    {
        float wA[128], wB[128];
        const float4* wra = (const float4*)(W1hh + rA * 128);
        const float4* wrb = (const float4*)(W1hh + rB * 128);
        #pragma unroll
        for (int k4 = 0; k4 < 32; ++k4) {
            float4 a = wra[k4], b = wrb[k4];
            wA[4*k4+0]=a.x; wA[4*k4+1]=a.y; wA[4*k4+2]=a.z; wA[4*k4+3]=a.w;
            wB[4*k4+0]=b.x; wB[4*k4+1]=b.y; wB[4*k4+2]=b.z; wB[4*k4+3]=b.w;
        }
        for (int tt = 0; tt < kT; ++tt) {
            const float4* hb4 = (const float4*)(sm + HB);
            float a0 = sm[ZX + tt * 512 + rA], a1 = 0.f;
            float b0 = sm[ZX + tt * 512 + rB], b1 = 0.f;
            #pragma unroll 8
            for (int k4 = 0; k4 < 32; k4 += 2) {
                float4 u = hb4[k4], v = hb4[k4 + 1];
                a0 = fmaf(wA[4*k4+0], u.x, a0); a0 = fmaf(wA[4*k4+1], u.y, a0);
                a0 = fmaf(wA[4*k4+2], u.z, a0); a0 = fmaf(wA[4*k4+3], u.w, a0);
                a1 = fmaf(wA[4*k4+4], v.x, a1); a1 = fmaf(wA[4*k4+5], v.y, a1);
                a1 = fmaf(wA[4*k4+6], v.z, a1); a1 = fmaf(wA[4*k4+7], v.w, a1);
                b0 = fmaf(wB[4*k4+0], u.x, b0); b0 = fmaf(wB[4*k4+1], u.y, b0);
                b0 = fmaf(wB[4*k4+2], u.z, b0); b0 = fmaf(wB[4*k4+3], u.w, b0);
                b1 = fmaf(wB[4*k4+4], v.x, b1); b1 = fmaf(wB[4*k4+5], v.y, b1);
                b1 = fmaf(wB[4*k4+6], v.z, b1); b1 = fmaf(wB[4*k4+7], v.w, b1);
            }
            float zA = a0 + a1, zB = b0 + b1;
            sm[ZB + rA] = fsig(zA);
            sm[ZB + rB] = (j < 128) ? ftanh(zB) : fsig(zB);
            __syncthreads();
            if (j < kSH) {
                float c = fmaf(sm[ZB + 128 + j], sm[CB + j], sm[ZB + j] * sm[ZB + 256 + j]);
                sm[CB + j] = c;
                sm[HB + j] = sm[ZB + 384 + j] * ftanh(c);
            }
            __syncthreads();
        }
    }
    // ---- MLP head ----
    if (j < 64) {
        float a0 = hb1[j], a1 = 0.f;
        #pragma unroll 8
        for (int k = 0; k < 128; k += 2) {
            a0 = fmaf(hW1[j * 128 + k],     sm[HB + k],     a0);
            a1 = fmaf(hW1[j * 128 + k + 1], sm[HB + k + 1], a1);
        }
        sm[ZB + j] = fmaxf(a0 + a1, 0.f);
    }
    __syncthreads();
    if (j < 32) {
        float acc = hb2[j];
        #pragma unroll 8
        for (int k = 0; k < 64; ++k) acc = fmaf(hW2[j * 64 + k], sm[ZB + k], acc);
        sm[ZB + 64 + j] = fmaxf(acc, 0.f);
    }
    __syncthreads();
    if (j == 0) {
        float acc = hb3[0];
        #pragma unroll
        for (int k = 0; k < 32; ++k) acc = fmaf(hW3[k], sm[ZB + 64 + k], acc);
        outp[bb] = fsig(acc);
    }
}

extern "C" void kernel_launch(void* const* d_in, const int* in_sizes, int n_in,
                              void* d_out, int out_size, void* d_ws, size_t ws_size,
                              hipStream_t stream) {
    const float* x     = (const float*)d_in[0];
    const int*   eidx  = (const int*)  d_in[1];
    const float* projW = (const float*)d_in[2];
    const float* projb = (const float*)d_in[3];
    const float* gWl   = (const float*)d_in[4];
    const float* gWr   = (const float*)d_in[5];
    const float* gatt  = (const float*)d_in[6];
    const float* gb    = (const float*)d_in[7];
    const float* lng   = (const float*)d_in[8];
    const float* lnb   = (const float*)d_in[9];
    const float* W0ih  = (const float*)d_in[10];
    const float* W0hh  = (const float*)d_in[11];
    const float* b0ih  = (const float*)d_in[12];
    const float* b0hh  = (const float*)d_in[13];
    const float* W1ih  = (const float*)d_in[14];
    const float* W1hh  = (const float*)d_in[15];
    const float* b1ih  = (const float*)d_in[16];
    const float* b1hh  = (const float*)d_in[17];
    const float* hW1   = (const float*)d_in[18];
    const float* hb1   = (const float*)d_in[19];
    const float* hW2   = (const float*)d_in[20];
    const float* hb2   = (const float*)d_in[21];
    const float* hW3   = (const float*)d_in[22];
    const float* hb3   = (const float*)d_in[23];
    float* outp = (float*)d_out;
    float* emb  = (float*)d_ws;   // [512][64] fp32 scratch

    (void)hipFuncSetAttribute((const void*)gat_kernel,
                              hipFuncAttributeMaxDynamicSharedMemorySize, (int)GAT_LDS);
    (void)hipFuncSetAttribute((const void*)lstm_head_kernel,
                              hipFuncAttributeMaxDynamicSharedMemorySize, (int)LSTM_LDS);

    hipLaunchKernelGGL(gat_kernel, dim3(kG), dim3(512), GAT_LDS, stream,
                       x, eidx, projW, projb, gWl, gWr, gatt, gb, lng, lnb, emb);
    hipLaunchKernelGGL(lstm_head_kernel, dim3(kB), dim3(256), LSTM_LDS, stream,
                       emb, W0ih, W0hh, b0ih, b0hh, W1ih, W1hh, b1ih, b1hh,
                       hW1, hb1, hW2, hb2, hW3, hb3, outp);
}

// Round 5
// 266.183 us; speedup vs baseline: 3.3120x; 3.3120x over previous
//
#include <hip/hip_runtime.h>
#include <math.h>

namespace {

constexpr int kB = 16, kT = 32, kN = 64, kE = 64, kFIN = 2, kD = 64, kH = 4, kL = 2, kSH = 128;
constexpr int kG = kB * kT;    // 512 graphs
constexpr int kET = kE + kN;   // 128 edges incl. self loops

// ---------------- GAT LDS layout (float indices) ----------------
constexpr int HN   = 0;                    // h[n][k] stride 68 (4352)
constexpr int XLo  = HN + 64 * 68;         // xl[4][64*65] (xl[hh*4160 + n*65 + d]) (16640)
constexpr int WREG = XLo + 4 * 4160;       // W staged [256][68] (17408); xr[4][4160] + tmp + LN scratch live here too
constexpr int XRo  = WREG;
constexpr int LG   = WREG + 256 * 68;      // logitT[4][128]
constexpr int AL   = LG + 4 * 128;         // alphaT[4][128]
constexpr int MB   = AL + 4 * 128;         // mT[4][64]
constexpr int SB   = MB + 4 * 64;          // 1/sum T[4][64]
constexpr int FEND = SB + 4 * 64;          // 39936 floats
// LN scratch in dead xr region (past tmp[64][65]):
constexpr int SC1 = XRo + 4160;
constexpr int SC2 = SC1 + 512;
constexpr int SMU = SC2 + 512;
constexpr int SRS = SMU + 64;
// int section
constexpr int ISRC = 0, IDST = 128, IOFF = 256, IEL = 321;
constexpr int NINT = IEL + 128;            // 449 ints
constexpr size_t GAT_LDS = size_t(FEND) * 4 + size_t(NINT) * 4;  // 161,540 B <= 163,840

// ---------------- LSTM LDS layout ----------------
constexpr int ES = 0;                  // embS[32][64]
constexpr int YS = ES + 32 * 64;       // ys[32][128]
constexpr int HB = YS + 32 * 128;      // h[128]
constexpr int CB = HB + 128;           // c[128]
constexpr int ZB = CB + 128;           // zbuf[512]
constexpr int ZX = ZB + 512;           // zx[32][512]
constexpr int LSTM_FLOATS = ZX + 32 * 512;
constexpr size_t LSTM_LDS = size_t(LSTM_FLOATS) * 4;  // 93,184 B

__device__ __forceinline__ float fsig(float x) {
    return __builtin_amdgcn_rcpf(1.f + __expf(-x));
}
__device__ __forceinline__ float ftanh(float x) {
    return 1.f - 2.f * __builtin_amdgcn_rcpf(1.f + __expf(2.f * x));
}
// wave-broadcast: value of v in lane l -> SGPR (feeds v_fmac's scalar operand)
__device__ __forceinline__ float rlane(float v, int l) {
    return __builtin_bit_cast(float, __builtin_amdgcn_readlane(__builtin_bit_cast(int, v), l));
}

} // namespace

// =====================================================================
// GAT kernel (UNCHANGED from R4): one block per graph, 512 threads.
// =====================================================================
__global__ __launch_bounds__(512, 2)
void gat_kernel(const float* __restrict__ x, const int* __restrict__ eidx,
                const float* __restrict__ projW, const float* __restrict__ projb,
                const float* __restrict__ gWl, const float* __restrict__ gWr,
                const float* __restrict__ gatt, const float* __restrict__ gb,
                const float* __restrict__ lng, const float* __restrict__ lnb,
                float* __restrict__ emb)
{
    extern __shared__ float sm[];
    int* ib = (int*)(sm + FEND);
    const int g = blockIdx.x;
    const int t = threadIdx.x;

    // ---- edges + self loops ----
    if (t < kET) {
        int s, d;
        if (t < kE) { s = eidx[g * 2 * kE + t]; d = eidx[g * 2 * kE + kE + t]; }
        else        { s = t - kE; d = s; }
        ib[ISRC + t] = s;
        ib[IDST + t] = d;
    }
    // ---- input projection + ReLU -> h[n][k] (stride 68) ----
    #pragma unroll
    for (int r = 0; r < 8; ++r) {
        int p = t + 512 * r;
        int d = p & 63, n = p >> 6;
        float x0 = x[g * kN * kFIN + n * kFIN + 0];
        float x1 = x[g * kN * kFIN + n * kFIN + 1];
        float v = fmaf(x0, projW[d * kFIN + 0], fmaf(x1, projW[d * kFIN + 1], projb[d]));
        sm[HN + n * 68 + d] = fmaxf(v, 0.f);
    }
    __syncthreads();
    // ---- CSR build (deterministic, no atomics) ----
    if (t < kN) {
        int c = 0;
        for (int e = 0; e < kET; ++e) c += (ib[IDST + e] == t) ? 1 : 0;
        ib[IOFF + t + 1] = c;
    }
    __syncthreads();
    if (t == 0) {
        ib[IOFF + 0] = 0;
        for (int n = 0; n < kN; ++n) ib[IOFF + n + 1] += ib[IOFF + n];
    }
    __syncthreads();
    if (t < kN) {
        int pos = ib[IOFF + t];
        for (int e = 0; e < kET; ++e)
            if (ib[IDST + e] == t) ib[IEL + pos++] = e;
    }
    __syncthreads();

    const int wv = t >> 6;
    const int ln = t & 63;
    const int cl = ln & 7;
    const int ng = ln >> 3;
    const int cwave = wv * 32;

    for (int l = 0; l < kL; ++l) {
        for (int half = 0; half < 2; ++half) {
            const float* Wg = (half ? gWr : gWl) + l * 256 * 64;
            #pragma unroll
            for (int it = 0; it < 8; ++it) {
                int p = t + 512 * it;
                float4 v = ((const float4*)Wg)[p];
                int c = p >> 4, k4 = p & 15;
                *(float4*)&sm[WREG + c * 68 + k4 * 4] = v;
            }
            __syncthreads();
            float acc[8][4];
            #pragma unroll
            for (int i = 0; i < 8; ++i)
                #pragma unroll
                for (int j = 0; j < 4; ++j) acc[i][j] = 0.f;
            #pragma unroll 2
            for (int k4 = 0; k4 < 16; ++k4) {
                float4 h4[8], w4[4];
                #pragma unroll
                for (int i = 0; i < 8; ++i)
                    h4[i] = *(const float4*)&sm[HN + (ng + 8 * i) * 68 + k4 * 4];
                #pragma unroll
                for (int j = 0; j < 4; ++j)
                    w4[j] = *(const float4*)&sm[WREG + (cwave + cl + 8 * j) * 68 + k4 * 4];
                #pragma unroll
                for (int i = 0; i < 8; ++i)
                    #pragma unroll
                    for (int j = 0; j < 4; ++j) {
                        acc[i][j] = fmaf(h4[i].x, w4[j].x, acc[i][j]);
                        acc[i][j] = fmaf(h4[i].y, w4[j].y, acc[i][j]);
                        acc[i][j] = fmaf(h4[i].z, w4[j].z, acc[i][j]);
                        acc[i][j] = fmaf(h4[i].w, w4[j].w, acc[i][j]);
                    }
            }
            __syncthreads();
            float* dst = sm + (half ? XRo : XLo);
            #pragma unroll
            for (int i = 0; i < 8; ++i) {
                int n = ng + 8 * i;
                #pragma unroll
                for (int j = 0; j < 4; ++j) {
                    int c = cwave + cl + 8 * j;
                    dst[(c >> 6) * 4160 + n * 65 + (c & 63)] = acc[i][j];
                }
            }
            __syncthreads();
        }
        // ---- edge logits ----
        {
            const int e = t & 127, hh = t >> 7;
            const int s = ib[ISRC + e], d_ = ib[IDST + e];
            const float* av = gatt + (l * kH + hh) * kD;
            const float* pl = sm + XLo + hh * 4160 + s * 65;
            const float* pr = sm + XRo + hh * 4160 + d_ * 65;
            float acc = 0.f;
            #pragma unroll 8
            for (int dd = 0; dd < 64; ++dd) {
                float v = pl[dd] + pr[dd];
                v = (v > 0.f) ? v : 0.2f * v;
                acc = fmaf(av[dd], v, acc);
            }
            sm[LG + hh * 128 + e] = acc;
        }
        __syncthreads();
        // ---- segment max & sum ----
        if (t < 256) {
            const int n = t & 63, hh = t >> 6;
            const int i0 = ib[IOFF + n], i1 = ib[IOFF + n + 1];
            float m = -3.0e38f;
            for (int i = i0; i < i1; ++i) m = fmaxf(m, sm[LG + hh * 128 + ib[IEL + i]]);
            float ssum = 0.f;
            for (int i = i0; i < i1; ++i) ssum += __expf(sm[LG + hh * 128 + ib[IEL + i]] - m);
            sm[MB + hh * 64 + n] = m;
            sm[SB + hh * 64 + n] = __builtin_amdgcn_rcpf(ssum);
        }
        __syncthreads();
        // ---- alpha ----
        {
            const int e = t & 127, hh = t >> 7;
            const int d_ = ib[IDST + e];
            sm[AL + hh * 128 + e] =
                __expf(sm[LG + hh * 128 + e] - sm[MB + hh * 64 + d_]) * sm[SB + hh * 64 + d_];
        }
        __syncthreads();
        // ---- aggregate + head-mean + bias -> tmp[64][65] at XRo ----
        #pragma unroll
        for (int r = 0; r < 8; ++r) {
            int p = t + 512 * r;
            int n = p >> 6, dd = p & 63;
            const int i0 = ib[IOFF + n], i1 = ib[IOFF + n + 1];
            float acc = 0.f;
            for (int i = i0; i < i1; ++i) {
                int e = ib[IEL + i];
                int s = ib[ISRC + e];
                const float* xs = sm + XLo + s * 65 + dd;
                acc = fmaf(sm[AL + 0 * 128 + e], xs[0 * 4160], acc);
                acc = fmaf(sm[AL + 1 * 128 + e], xs[1 * 4160], acc);
                acc = fmaf(sm[AL + 2 * 128 + e], xs[2 * 4160], acc);
                acc = fmaf(sm[AL + 3 * 128 + e], xs[3 * 4160], acc);
            }
            sm[XRo + n * 65 + dd] = acc * 0.25f + gb[l * kD + dd];
        }
        __syncthreads();
        // ---- layernorm partials ----
        {
            const int n = t >> 3, q = t & 7;
            const float* row = sm + XRo + n * 65 + q * 8;
            float s1 = 0.f, s2 = 0.f;
            #pragma unroll
            for (int i = 0; i < 8; ++i) { float v = row[i]; s1 += v; s2 = fmaf(v, v, s2); }
            sm[SC1 + n * 8 + q] = s1;
            sm[SC2 + n * 8 + q] = s2;
        }
        __syncthreads();
        if (t < kN) {
            float s1 = 0.f, s2 = 0.f;
            #pragma unroll
            for (int q = 0; q < 8; ++q) { s1 += sm[SC1 + t * 8 + q]; s2 += sm[SC2 + t * 8 + q]; }
            float m   = s1 * (1.f / 64.f);
            float var = s2 * (1.f / 64.f) - m * m;
            sm[SMU + t] = m;
            sm[SRS + t] = rsqrtf(var + 1e-5f);
        }
        __syncthreads();
        // ---- apply LN + ReLU -> h[n][k] ----
        #pragma unroll
        for (int r = 0; r < 8; ++r) {
            int p = t + 512 * r;
            int dd = p & 63, n = p >> 6;
            float v  = sm[XRo + n * 65 + dd];
            float y  = fmaf(lng[l * kD + dd] * (v - sm[SMU + n]), sm[SRS + n], lnb[l * kD + dd]);
            sm[HN + n * 68 + dd] = fmaxf(y, 0.f);
        }
        __syncthreads();
    }
    // ---- global mean pool ----
    if (t < kD) {
        float s = 0.f;
        #pragma unroll 8
        for (int n = 0; n < kN; ++n) s += sm[HN + n * 68 + t];
        emb[g * kD + t] = s * (1.f / 64.f);
    }
}

// =====================================================================
// LSTM (2 layers, T=32) + MLP head: one block per batch element (16),
// 512 threads, one gate-row per thread (w[128] in VGPR, ~170 regs).
// Broadcast operands via v_readlane -> SGPR -> v_fmac(vgpr, sgpr):
// 2 ds_read_b32 per wave per step instead of 32 ds_read_b128.
// =====================================================================
__global__ __launch_bounds__(512, 1)
void lstm_head_kernel(const float* __restrict__ emb,
                      const float* __restrict__ W0ih, const float* __restrict__ W0hh,
                      const float* __restrict__ b0ih, const float* __restrict__ b0hh,
                      const float* __restrict__ W1ih, const float* __restrict__ W1hh,
                      const float* __restrict__ b1ih, const float* __restrict__ b1hh,
                      const float* __restrict__ hW1, const float* __restrict__ hb1,
                      const float* __restrict__ hW2, const float* __restrict__ hb2,
                      const float* __restrict__ hW3, const float* __restrict__ hb3,
                      float* __restrict__ outp)
{
    extern __shared__ float sm[];
    const int bb = blockIdx.x;
    const int j  = threadIdx.x;      // 0..511
    const int ln = j & 63;
    const int gate = j >> 7;         // wave-uniform (2 waves per gate)

    // full emb staging: 512 threads x float4 = 2048 floats
    ((float4*)(sm + ES))[j] = ((const float4*)(emb + bb * kT * kD))[j];
    if (j < kSH) { sm[HB + j] = 0.f; sm[CB + j] = 0.f; }
    __syncthreads();

    // ---- layer0 x-part: zx[t][j] = bias + W0ih[j,:]·emb[t,:] (readlane bcast) ----
    {
        float w[64];
        const float4* wr = (const float4*)(W0ih + j * 64);
        #pragma unroll
        for (int k4 = 0; k4 < 16; ++k4) {
            float4 v = wr[k4];
            w[4*k4+0] = v.x; w[4*k4+1] = v.y; w[4*k4+2] = v.z; w[4*k4+3] = v.w;
        }
        const float bias = b0ih[j] + b0hh[j];
        for (int tt = 0; tt < kT; ++tt) {
            float ev = sm[ES + tt * 64 + ln];     // lane l holds emb[t][l]
            float a0 = bias, a1 = 0.f, a2 = 0.f, a3 = 0.f;
            #pragma unroll
            for (int k = 0; k < 64; k += 4) {
                a0 = fmaf(w[k + 0], rlane(ev, k + 0), a0);
                a1 = fmaf(w[k + 1], rlane(ev, k + 1), a1);
                a2 = fmaf(w[k + 2], rlane(ev, k + 2), a2);
                a3 = fmaf(w[k + 3], rlane(ev, k + 3), a3);
            }
            sm[ZX + tt * 512 + j] = (a0 + a1) + (a2 + a3);
        }
    }
    __syncthreads();
    // ---- layer0 recurrence ----
    {
        float w[128];
        const float4* wr = (const float4*)(W0hh + j * 128);
        #pragma unroll
        for (int k4 = 0; k4 < 32; ++k4) {
            float4 v = wr[k4];
            w[4*k4+0] = v.x; w[4*k4+1] = v.y; w[4*k4+2] = v.z; w[4*k4+3] = v.w;
        }
        for (int tt = 0; tt < kT; ++tt) {
            float hlo = sm[HB + ln];
            float hhi = sm[HB + 64 + ln];
            float a0 = sm[ZX + tt * 512 + j], a1 = 0.f, a2 = 0.f, a3 = 0.f;
            #pragma unroll
            for (int k = 0; k < 64; k += 4) {
                a0 = fmaf(w[k + 0], rlane(hlo, k + 0), a0);
                a1 = fmaf(w[k + 1], rlane(hlo, k + 1), a1);
                a2 = fmaf(w[k + 2], rlane(hlo, k + 2), a2);
                a3 = fmaf(w[k + 3], rlane(hlo, k + 3), a3);
            }
            #pragma unroll
            for (int k = 0; k < 64; k += 4) {
                a0 = fmaf(w[64 + k + 0], rlane(hhi, k + 0), a0);
                a1 = fmaf(w[64 + k + 1], rlane(hhi, k + 1), a1);
                a2 = fmaf(w[64 + k + 2], rlane(hhi, k + 2), a2);
                a3 = fmaf(w[64 + k + 3], rlane(hhi, k + 3), a3);
            }
            float zv = (a0 + a1) + (a2 + a3);
            sm[ZB + j] = (gate == 2) ? ftanh(zv) : fsig(zv);
            __syncthreads();
            if (j < kSH) {
                float c = fmaf(sm[ZB + 128 + j], sm[CB + j], sm[ZB + j] * sm[ZB + 256 + j]);
                sm[CB + j] = c;
                float h = sm[ZB + 384 + j] * ftanh(c);
                sm[HB + j] = h;
                sm[YS + tt * 128 + j] = h;
            }
            __syncthreads();
        }
    }
    // ---- layer1 x-part: zx[t][j] = bias + W1ih[j,:]·ys[t,:] ----
    {
        float w[128];
        const float4* wr = (const float4*)(W1ih + j * 128);
        #pragma unroll
        for (int k4 = 0; k4 < 32; ++k4) {
            float4 v = wr[k4];
            w[4*k4+0] = v.x; w[4*k4+1] = v.y; w[4*k4+2] = v.z; w[4*k4+3] = v.w;
        }
        const float bias = b1ih[j] + b1hh[j];
        for (int tt = 0; tt < kT; ++tt) {
            float ylo = sm[YS + tt * 128 + ln];
            float yhi = sm[YS + tt * 128 + 64 + ln];
            float a0 = bias, a1 = 0.f, a2 = 0.f, a3 = 0.f;
            #pragma unroll
            for (int k = 0; k < 64; k += 4) {
                a0 = fmaf(w[k + 0], rlane(ylo, k + 0), a0);
                a1 = fmaf(w[k + 1], rlane(ylo, k + 1), a1);
                a2 = fmaf(w[k + 2], rlane(ylo, k + 2), a2);
                a3 = fmaf(w[k + 3], rlane(ylo, k + 3), a3);
            }
            #pragma unroll
            for (int k = 0; k < 64; k += 4) {
                a0 = fmaf(w[64 + k + 0], rlane(yhi, k + 0), a0);
                a1 = fmaf(w[64 + k + 1], rlane(yhi, k + 1), a1);
                a2 = fmaf(w[64 + k + 2], rlane(yhi, k + 2), a2);
                a3 = fmaf(w[64 + k + 3], rlane(yhi, k + 3), a3);
            }
            sm[ZX + tt * 512 + j] = (a0 + a1) + (a2 + a3);
        }
    }
    if (j < kSH) { sm[HB + j] = 0.f; sm[CB + j] = 0.f; }
    __syncthreads();
    // ---- layer1 recurrence (keep only final h) ----
    {
        float w[128];
        const float4* wr = (const float4*)(W1hh + j * 128);
        #pragma unroll
        for (int k4 = 0; k4 < 32; ++k4) {
            float4 v = wr[k4];
            w[4*k4+0] = v.x; w[4*k4+1] = v.y; w[4*k4+2] = v.z; w[4*k4+3] = v.w;
        }
        for (int tt = 0; tt < kT; ++tt) {
            float hlo = sm[HB + ln];
            float hhi = sm[HB + 64 + ln];
            float a0 = sm[ZX + tt * 512 + j], a1 = 0.f, a2 = 0.f, a3 = 0.f;
            #pragma unroll
            for (int k = 0; k < 64; k += 4) {
                a0 = fmaf(w[k + 0], rlane(hlo, k + 0), a0);
                a1 = fmaf(w[k + 1], rlane(hlo, k + 1), a1);
                a2 = fmaf(w[k + 2], rlane(hlo, k + 2), a2);
                a3 = fmaf(w[k + 3], rlane(hlo, k + 3), a3);
            }
            #pragma unroll
            for (int k = 0; k < 64; k += 4) {
                a0 = fmaf(w[64 + k + 0], rlane(hhi, k + 0), a0);
                a1 = fmaf(w[64 + k + 1], rlane(hhi, k + 1), a1);
                a2 = fmaf(w[64 + k + 2], rlane(hhi, k + 2), a2);
                a3 = fmaf(w[64 + k + 3], rlane(hhi, k + 3), a3);
            }
            float zv = (a0 + a1) + (a2 + a3);
            sm[ZB + j] = (gate == 2) ? ftanh(zv) : fsig(zv);
            __syncthreads();
            if (j < kSH) {
                float c = fmaf(sm[ZB + 128 + j], sm[CB + j], sm[ZB + j] * sm[ZB + 256 + j]);
                sm[CB + j] = c;
                sm[HB + j] = sm[ZB + 384 + j] * ftanh(c);
            }
            __syncthreads();
        }
    }
    // ---- MLP head ----
    if (j < 64) {
        float a0 = hb1[j], a1 = 0.f;
        #pragma unroll 8
        for (int k = 0; k < 128; k += 2) {
            a0 = fmaf(hW1[j * 128 + k],     sm[HB + k],     a0);
            a1 = fmaf(hW1[j * 128 + k + 1], sm[HB + k + 1], a1);
        }
        sm[ZB + j] = fmaxf(a0 + a1, 0.f);
    }
    __syncthreads();
    if (j < 32) {
        float acc = hb2[j];
        #pragma unroll 8
        for (int k = 0; k < 64; ++k) acc = fmaf(hW2[j * 64 + k], sm[ZB + k], acc);
        sm[ZB + 64 + j] = fmaxf(acc, 0.f);
    }
    __syncthreads();
    if (j == 0) {
        float acc = hb3[0];
        #pragma unroll
        for (int k = 0; k < 32; ++k) acc = fmaf(hW3[k], sm[ZB + 64 + k], acc);
        outp[bb] = fsig(acc);
    }
}

extern "C" void kernel_launch(void* const* d_in, const int* in_sizes, int n_in,
                              void* d_out, int out_size, void* d_ws, size_t ws_size,
                              hipStream_t stream) {
    const float* x     = (const float*)d_in[0];
    const int*   eidx  = (const int*)  d_in[1];
    const float* projW = (const float*)d_in[2];
    const float* projb = (const float*)d_in[3];
    const float* gWl   = (const float*)d_in[4];
    const float* gWr   = (const float*)d_in[5];
    const float* gatt  = (const float*)d_in[6];
    const float* gb    = (const float*)d_in[7];
    const float* lng   = (const float*)d_in[8];
    const float* lnb   = (const float*)d_in[9];
    const float* W0ih  = (const float*)d_in[10];
    const float* W0hh  = (const float*)d_in[11];
    const float* b0ih  = (const float*)d_in[12];
    const float* b0hh  = (const float*)d_in[13];
    const float* W1ih  = (const float*)d_in[14];
    const float* W1hh  = (const float*)d_in[15];
    const float* b1ih  = (const float*)d_in[16];
    const float* b1hh  = (const float*)d_in[17];
    const float* hW1   = (const float*)d_in[18];
    const float* hb1   = (const float*)d_in[19];
    const float* hW2   = (const float*)d_in[20];
    const float* hb2   = (const float*)d_in[21];
    const float* hW3   = (const float*)d_in[22];
    const float* hb3   = (const float*)d_in[23];
    float* outp = (float*)d_out;
    float* emb  = (float*)d_ws;   // [512][64] fp32 scratch

    (void)hipFuncSetAttribute((const void*)gat_kernel,
                              hipFuncAttributeMaxDynamicSharedMemorySize, (int)GAT_LDS);
    (void)hipFuncSetAttribute((const void*)lstm_head_kernel,
                              hipFuncAttributeMaxDynamicSharedMemorySize, (int)LSTM_LDS);

    hipLaunchKernelGGL(gat_kernel, dim3(kG), dim3(512), GAT_LDS, stream,
                       x, eidx, projW, projb, gWl, gWr, gatt, gb, lng, lnb, emb);
    hipLaunchKernelGGL(lstm_head_kernel, dim3(kB), dim3(512), LSTM_LDS, stream,
                       emb, W0ih, W0hh, b0ih, b0hh, W1ih, W1hh, b1ih, b1hh,
                       hW1, hb1, hW2, hb2, hW3, hb3, outp);
}